// Round 8
// baseline (394.688 us; speedup 1.0000x reference)
//
#include <hip/hip_runtime.h>
#include <hip/hip_fp16.h>

// ---------------- utility kernels ----------------

__global__ void k_zero_i32(int* __restrict__ p, int n) {
    int i = blockIdx.x * blockDim.x + threadIdx.x;
    if (i < n) p[i] = 0;
}

__global__ void k_count(const int* __restrict__ col, int E, int* __restrict__ cnt) {
    int e = blockIdx.x * blockDim.x + threadIdx.x;
    if (e < E) atomicAdd(&cnt[col[e]], 1);
}

// ---- 3-pass parallel exclusive scan over cnt[0..N) -> starts[0..N] ----
__global__ void k_bsum(const int* __restrict__ cnt, int N, int* __restrict__ bsum) {
    __shared__ int wt[4];
    int t = threadIdx.x;
    int i0 = blockIdx.x * 1024 + t * 4;
    int s = 0;
    #pragma unroll
    for (int j = 0; j < 4; ++j) { int i = i0 + j; if (i < N) s += cnt[i]; }
    #pragma unroll
    for (int off = 32; off > 0; off >>= 1) s += __shfl_down(s, off, 64);
    if ((t & 63) == 0) wt[t >> 6] = s;
    __syncthreads();
    if (t == 0) bsum[blockIdx.x] = wt[0] + wt[1] + wt[2] + wt[3];
}

__global__ void k_bscan(int* __restrict__ bsum, int nb, int* __restrict__ starts, int N) {
    int lane = threadIdx.x;
    int carry = 0;
    for (int base = 0; base < nb; base += 64) {
        int i = base + lane;
        int v = (i < nb) ? bsum[i] : 0;
        int s = v;
        #pragma unroll
        for (int off = 1; off < 64; off <<= 1) {
            int u = __shfl_up(s, off, 64);
            if (lane >= off) s += u;
        }
        if (i < nb) bsum[i] = carry + s - v;
        carry += __shfl(s, 63, 64);
    }
    if (lane == 0) starts[N] = carry;
}

__global__ void k_scan_apply(const int* __restrict__ cnt, const int* __restrict__ bsum,
                             int* __restrict__ starts, int N) {
    __shared__ int wt[4];
    int t = threadIdx.x;
    int lane = t & 63;
    int w = t >> 6;
    int i0 = blockIdx.x * 1024 + t * 4;
    int v[4];
    int ts = 0;
    #pragma unroll
    for (int j = 0; j < 4; ++j) { int i = i0 + j; v[j] = (i < N) ? cnt[i] : 0; ts += v[j]; }
    int s = ts;
    #pragma unroll
    for (int off = 1; off < 64; off <<= 1) {
        int u = __shfl_up(s, off, 64);
        if (lane >= off) s += u;
    }
    if (lane == 63) wt[w] = s;
    __syncthreads();
    int woff = 0;
    if (w > 0) woff = wt[0];
    if (w > 1) woff += wt[1];
    if (w > 2) woff += wt[2];
    int base = bsum[blockIdx.x] + woff + (s - ts);
    int run = base;
    #pragma unroll
    for (int j = 0; j < 4; ++j) { int i = i0 + j; if (i < N) starts[i] = run; run += v[j]; }
}

__global__ void k_dinv(const int* __restrict__ starts, float* __restrict__ dinv, int N) {
    int i = blockIdx.x * blockDim.x + threadIdx.x;
    if (i < N) dinv[i] = rsqrtf((float)(starts[i + 1] - starts[i]) + 1.0f);
}

// XCD-windowed CSR fill: group w = blockIdx&7 handles cols [w*W, w*W+W).
__global__ void k_fill_xcd(const int* __restrict__ row, const int* __restrict__ col, int E,
                           const int* __restrict__ starts, int* __restrict__ cnt,
                           int* __restrict__ csr, int N) {
    const int w = blockIdx.x & 7;
    const int chunk = blockIdx.x >> 3;
    const int nchunks = gridDim.x >> 3;
    const int W = (N + 7) / 8;
    const int c0 = w * W;
    const int c1 = min(N, c0 + W);
    const int stride = nchunks * blockDim.x;
    for (int e = chunk * blockDim.x + threadIdx.x; e < E; e += stride) {
        int c = col[e];
        if (c >= c0 && c < c1) {
            int pos = starts[c] + atomicSub(&cnt[c], 1) - 1;
            csr[pos] = row[e];
        }
    }
}

// x fp32 -> fp16
__global__ void k_f2h(const float* __restrict__ src, __half* __restrict__ dst, long n) {
    long i = ((long)blockIdx.x * blockDim.x + threadIdx.x) * 4;
    if (i + 3 < n) {
        float4 v = *(const float4*)&src[i];
        __half2 h0 = __floats2half2_rn(v.x, v.y);
        __half2 h1 = __floats2half2_rn(v.z, v.w);
        uint2 q; q.x = *(unsigned int*)&h0; q.y = *(unsigned int*)&h1;
        *(uint2*)&dst[i] = q;
    } else {
        for (long j = i; j < n; ++j) dst[j] = __float2half_rn(src[j]);
    }
}

// ---------------- tiled fp32 GEMM, templated output ----------------

template<typename OT, int K, int M, int BN, bool BIAS, bool RELU>
__global__ void k_gemm_t(const float* __restrict__ X, const float* __restrict__ W,
                         OT* __restrict__ P, const float* __restrict__ bias, int N) {
    constexpr int TM = 8;
    constexpr int TN = 4;
    constexpr int TMN = M / TM;
    constexpr int TNN = BN / TN;
    constexpr int NT = TMN * TNN;
    constexpr int KC = 64;
    constexpr int MH = M / 2;
    constexpr int XLD = KC + 1;
    __shared__ float Wl[KC * M];
    __shared__ float Xl[BN * XLD];
    const int t = threadIdx.x;
    const int tm = t % TMN;
    const int tn = t / TMN;
    const int n0 = blockIdx.x * BN;
    float acc[TN][TM] = {};
    for (int k0 = 0; k0 < K; k0 += KC) {
        #pragma unroll
        for (int i = t * 4; i < KC * M; i += NT * 4)
            *(float4*)&Wl[i] = *(const float4*)&W[(long)k0 * M + i];
        {
            const int kq = t % (KC / 4);
            const int nl0 = t / (KC / 4);
            constexpr int NPN = NT / (KC / 4);
            #pragma unroll
            for (int p = 0; p < BN / NPN; ++p) {
                int n = nl0 + p * NPN;
                int gn = n0 + n;
                float4 v = make_float4(0.f, 0.f, 0.f, 0.f);
                if (gn < N) v = *(const float4*)&X[(long)gn * K + k0 + kq * 4];
                float* xr = &Xl[n * XLD + kq * 4];
                xr[0] = v.x; xr[1] = v.y; xr[2] = v.z; xr[3] = v.w;
            }
        }
        __syncthreads();
        #pragma unroll 4
        for (int k = 0; k < KC; ++k) {
            float4 w0 = *(float4*)&Wl[k * M + tm * 4];
            float4 w1 = *(float4*)&Wl[k * M + MH + tm * 4];
            float xs[TN];
            #pragma unroll
            for (int i = 0; i < TN; ++i) xs[i] = Xl[(tn * TN + i) * XLD + k];
            #pragma unroll
            for (int i = 0; i < TN; ++i) {
                acc[i][0] += xs[i] * w0.x;
                acc[i][1] += xs[i] * w0.y;
                acc[i][2] += xs[i] * w0.z;
                acc[i][3] += xs[i] * w0.w;
                acc[i][4] += xs[i] * w1.x;
                acc[i][5] += xs[i] * w1.y;
                acc[i][6] += xs[i] * w1.z;
                acc[i][7] += xs[i] * w1.w;
            }
        }
        __syncthreads();
    }
    float4 bb0 = make_float4(0.f, 0.f, 0.f, 0.f), bb1 = bb0;
    if (BIAS) {
        bb0 = *(const float4*)&bias[tm * 4];
        bb1 = *(const float4*)&bias[MH + tm * 4];
    }
    #pragma unroll
    for (int i = 0; i < TN; ++i) {
        int gn = n0 + tn * TN + i;
        if (gn >= N) continue;
        float4 a0 = make_float4(acc[i][0], acc[i][1], acc[i][2], acc[i][3]);
        float4 a1 = make_float4(acc[i][4], acc[i][5], acc[i][6], acc[i][7]);
        if (BIAS) {
            a0.x += bb0.x; a0.y += bb0.y; a0.z += bb0.z; a0.w += bb0.w;
            a1.x += bb1.x; a1.y += bb1.y; a1.z += bb1.z; a1.w += bb1.w;
        }
        if (RELU) {
            a0.x = fmaxf(a0.x, 0.f); a0.y = fmaxf(a0.y, 0.f);
            a0.z = fmaxf(a0.z, 0.f); a0.w = fmaxf(a0.w, 0.f);
            a1.x = fmaxf(a1.x, 0.f); a1.y = fmaxf(a1.y, 0.f);
            a1.z = fmaxf(a1.z, 0.f); a1.w = fmaxf(a1.w, 0.f);
        }
        if constexpr (__is_same(OT, float)) {
            *(float4*)&P[(long)gn * M + tm * 4] = a0;
            *(float4*)&P[(long)gn * M + MH + tm * 4] = a1;
        } else {
            __half2 h0 = __floats2half2_rn(a0.x, a0.y);
            __half2 h1 = __floats2half2_rn(a0.z, a0.w);
            __half2 h2 = __floats2half2_rn(a1.x, a1.y);
            __half2 h3 = __floats2half2_rn(a1.z, a1.w);
            uint2 q0; q0.x = *(unsigned int*)&h0; q0.y = *(unsigned int*)&h1;
            uint2 q1; q1.x = *(unsigned int*)&h2; q1.y = *(unsigned int*)&h3;
            *(uint2*)&P[(long)gn * M + tm * 4] = q0;
            *(uint2*)&P[(long)gn * M + MH + tm * 4] = q1;
        }
    }
}

// ---------------- line-aligned XCD feature-split fp16-gather aggregation ----
// GROUPS groups, each covering FPG = M/GROUPS features = exactly 64B (one
// cache line) of an fp16 row -> no line shared between groups. With
// round-robin blockIdx->XCD, group g = blockIdx&(GROUPS-1) sticks to a
// disjoint XCD subset -> per-XCD gather working set = N*FPG*2B = 3.2MB < L2.

template<int M, int GROUPS, bool BIAS, bool RELU>
__global__ void k_agg16s(const __half* __restrict__ P16, const int* __restrict__ starts,
                         const int* __restrict__ csr, const float* __restrict__ dinv,
                         const float* __restrict__ b, float* __restrict__ H, int N) {
    constexpr int FPG = M / GROUPS;        // features per group (32)
    constexpr int LPN = FPG / 8;           // lanes per node (4)
    constexpr int NPB = 256 / LPN;         // nodes per block (64)
    static_assert(FPG * 2 == 64, "group slice must be exactly one 64B line");
    const int g = blockIdx.x & (GROUPS - 1);
    const int blk = blockIdx.x / GROUPS;
    const int lane = threadIdx.x % LPN;
    const int local = threadIdx.x / LPN;
    const int c = blk * NPB + local;
    if (c >= N) return;
    const int f0 = g * FPG + lane * 8;
    int i = starts[c], e = starts[c + 1];
    float acc[8] = {};
    for (; i + 1 < e; i += 2) {
        int r0 = csr[i], r1 = csr[i + 1];
        float d0 = dinv[r0], d1 = dinv[r1];
        uint4 u0 = *(const uint4*)&P16[(long)r0 * M + f0];
        uint4 u1 = *(const uint4*)&P16[(long)r1 * M + f0];
        const __half2* h0 = (const __half2*)&u0;
        const __half2* h1 = (const __half2*)&u1;
        #pragma unroll
        for (int j = 0; j < 4; ++j) {
            float2 f0v = __half22float2(h0[j]);
            float2 f1v = __half22float2(h1[j]);
            acc[2 * j]     += f0v.x * d0 + f1v.x * d1;
            acc[2 * j + 1] += f0v.y * d0 + f1v.y * d1;
        }
    }
    if (i < e) {
        int r0 = csr[i];
        float d0 = dinv[r0];
        uint4 u0 = *(const uint4*)&P16[(long)r0 * M + f0];
        const __half2* h0 = (const __half2*)&u0;
        #pragma unroll
        for (int j = 0; j < 4; ++j) {
            float2 f0v = __half22float2(h0[j]);
            acc[2 * j]     += f0v.x * d0;
            acc[2 * j + 1] += f0v.y * d0;
        }
    }
    float dc = dinv[c];
    float dc2 = dc * dc;
    uint4 us = *(const uint4*)&P16[(long)c * M + f0];
    const __half2* hs = (const __half2*)&us;
    float v[8];
    #pragma unroll
    for (int j = 0; j < 4; ++j) {
        float2 fs = __half22float2(hs[j]);
        v[2 * j]     = dc * acc[2 * j]     + dc2 * fs.x;
        v[2 * j + 1] = dc * acc[2 * j + 1] + dc2 * fs.y;
    }
    if (BIAS) {
        float4 bb0 = *(const float4*)&b[f0];
        float4 bb1 = *(const float4*)&b[f0 + 4];
        v[0] += bb0.x; v[1] += bb0.y; v[2] += bb0.z; v[3] += bb0.w;
        v[4] += bb1.x; v[5] += bb1.y; v[6] += bb1.z; v[7] += bb1.w;
    }
    if (RELU) {
        #pragma unroll
        for (int j = 0; j < 8; ++j) v[j] = fmaxf(v[j], 0.f);
    }
    *(float4*)&H[(long)c * M + f0]     = make_float4(v[0], v[1], v[2], v[3]);
    *(float4*)&H[(long)c * M + f0 + 4] = make_float4(v[4], v[5], v[6], v[7]);
}

// ---------------- fp32 fallback kernels (unexpected shapes) ----------------

__global__ void k_gemm_naive(const float* __restrict__ X, const float* __restrict__ W,
                             float* __restrict__ P, int N, int K, int M) {
    long idx = (long)blockIdx.x * blockDim.x + threadIdx.x;
    long total = (long)N * M;
    if (idx >= total) return;
    int n = (int)(idx / M);
    int m = (int)(idx - (long)n * M);
    const float* xr = X + (long)n * K;
    float acc = 0.0f;
    for (int k = 0; k < K; ++k) acc += xr[k] * W[k * M + m];
    P[idx] = acc;
}

template<int M>
__global__ void k_aggregate4(const float* __restrict__ P, const int* __restrict__ starts,
                             const int* __restrict__ csr, const float* __restrict__ dinv,
                             const float* __restrict__ b, float* __restrict__ H,
                             int N, int do_relu) {
    constexpr int TPN = M / 4;
    constexpr int NPB = 256 / TPN;
    int local = threadIdx.x / TPN;
    int fq = threadIdx.x % TPN;
    int c = blockIdx.x * NPB + local;
    if (c >= N) return;
    int s = starts[c], e = starts[c + 1];
    float4 acc = make_float4(0.f, 0.f, 0.f, 0.f);
    for (int i = s; i < e; ++i) {
        int r = csr[i];
        float dr = dinv[r];
        float4 p = *(const float4*)&P[(long)r * M + fq * 4];
        acc.x += p.x * dr; acc.y += p.y * dr; acc.z += p.z * dr; acc.w += p.w * dr;
    }
    float dc = dinv[c];
    float dc2 = dc * dc;
    float4 ps = *(const float4*)&P[(long)c * M + fq * 4];
    float4 bb = *(const float4*)&b[fq * 4];
    float4 v;
    v.x = dc * acc.x + dc2 * ps.x + bb.x;
    v.y = dc * acc.y + dc2 * ps.y + bb.y;
    v.z = dc * acc.z + dc2 * ps.z + bb.z;
    v.w = dc * acc.w + dc2 * ps.w + bb.w;
    if (do_relu) {
        v.x = fmaxf(v.x, 0.f); v.y = fmaxf(v.y, 0.f);
        v.z = fmaxf(v.z, 0.f); v.w = fmaxf(v.w, 0.f);
    }
    *(float4*)&H[(long)c * M + fq * 4] = v;
}

// ---------------- pooling + classifier ----------------

__device__ __forceinline__ int lower_bound_i(const int* __restrict__ a, int n, int key) {
    int lo = 0, hi = n;
    while (lo < hi) { int mid = (lo + hi) >> 1; if (a[mid] < key) lo = mid + 1; else hi = mid; }
    return lo;
}

__global__ void k_pool(const float* __restrict__ H, const int* __restrict__ batch,
                       int N, int M, float* __restrict__ pooled) {
    int g = blockIdx.x;
    int f = threadIdx.x;       // blockDim.x == M
    int lo = lower_bound_i(batch, N, g);
    int hi = lower_bound_i(batch, N, g + 1);
    float acc = 0.0f;
    for (int n = lo; n < hi; ++n) acc += H[(long)n * M + f];
    float inv = 1.0f / fmaxf((float)(hi - lo), 1.0f);
    pooled[(long)g * M + f] = acc * inv;
}

__global__ void k_final(const float* __restrict__ pooled, const float* __restrict__ Wl,
                        const float* __restrict__ bl, float* __restrict__ out,
                        int Gn, int F, int C) {
    int idx = blockIdx.x * blockDim.x + threadIdx.x;
    if (idx >= Gn * C) return;
    int g = idx / C;
    int j = idx - g * C;
    float acc = bl[j];
    for (int f = 0; f < F; ++f) acc += pooled[g * F + f] * Wl[f * C + j];
    out[idx] = acc;
}

// ---------------- launch ----------------

extern "C" void kernel_launch(void* const* d_in, const int* in_sizes, int n_in,
                              void* d_out, int out_size, void* d_ws, size_t ws_size,
                              hipStream_t stream) {
    const float* x  = (const float*)d_in[0];
    const int*   ei = (const int*)d_in[1];
    const int*   batch = (const int*)d_in[2];
    const float* W1 = (const float*)d_in[3];
    const float* b1 = (const float*)d_in[4];
    const float* W2 = (const float*)d_in[5];
    const float* b2 = (const float*)d_in[6];
    const float* W3 = (const float*)d_in[7];
    const float* b3 = (const float*)d_in[8];
    const float* Wl = (const float*)d_in[9];
    const float* bl = (const float*)d_in[10];

    const int N  = in_sizes[2];          // 50000
    const int E  = in_sizes[1] / 2;      // 800000
    const int C  = in_sizes[10];         // 10
    const int Gn = out_size / C;         // 512
    const int F1 = in_sizes[4];          // 128
    const int F2 = in_sizes[6];          // 128
    const int F3 = in_sizes[8];          // 64
    const int K0 = in_sizes[0] / N;      // 64

    const int* row = ei;
    const int* col = ei + E;

    // workspace layout
    int* cnt    = (int*)d_ws;                 // N
    int* starts = cnt + N;                    // N+1
    int* bsum   = starts + N + 1;             // 256
    int* csr    = bsum + 256;                 // E
    float* dinv = (float*)(csr + E);          // N
    float* A    = dinv + N;                   // N*128 f32
    float* B    = A + (long)N * 128;          // N*128 f32
    float* pooled = B + (long)N * 128;        // Gn*64

    // aliases inside A (time-disjoint)
    float*  AX   = A;                               // [N,64] f32
    __half* X16  = (__half*)(A + (long)N * 64);     // [N,64] f16
    __half* P16a = (__half*)A;                      // [N,128] f16
    __half* P16b = (__half*)A;                      // [N,64] f16
    float*  H3   = A + (long)N * 64;                // [N,64] f32

    const int BLK = 256;
    auto blocks = [](long n, int b) { return (int)((n + b - 1) / b); };
    const int nb = blocks(N, 1024);

    // --- build CSR ---
    k_zero_i32<<<blocks(N, BLK), BLK, 0, stream>>>(cnt, N);
    k_count<<<blocks(E, BLK), BLK, 0, stream>>>(col, E, cnt);
    k_bsum<<<nb, 256, 0, stream>>>(cnt, N, bsum);
    k_bscan<<<1, 64, 0, stream>>>(bsum, nb, starts, N);
    k_scan_apply<<<nb, 256, 0, stream>>>(cnt, bsum, starts, N);
    k_dinv<<<blocks(N, BLK), BLK, 0, stream>>>(starts, dinv, N);
    k_fill_xcd<<<128 * 8, 256, 0, stream>>>(row, col, E, starts, cnt, csr, N);

    const bool fast = (K0 == 64 && F1 == 128 && F2 == 128 && F3 == 64);

    if (fast) {
        // --- layer 1 (reordered): H1 = relu( (A_hat X) W1 + b1 ) ---
        k_f2h<<<blocks(((long)N * 64 + 3) / 4, BLK), BLK, 0, stream>>>(x, X16, (long)N * 64);
        k_agg16s<64, 2, false, false><<<2 * blocks(N, 64), 256, 0, stream>>>(X16, starts, csr, dinv, nullptr, AX, N);
        k_gemm_t<float, 64, 128, 64, true, true><<<blocks(N, 64), 256, 0, stream>>>(AX, W1, B, b1, N);
        // --- layer 2: H2 = relu( A_hat (H1 W2) + b2 ) ---
        k_gemm_t<__half, 128, 128, 64, false, false><<<blocks(N, 64), 256, 0, stream>>>(B, W2, P16a, nullptr, N);
        k_agg16s<128, 4, true, true><<<4 * blocks(N, 64), 256, 0, stream>>>(P16a, starts, csr, dinv, b2, B, N);
        // --- layer 3: H3 = A_hat (H2 W3) + b3 ---
        k_gemm_t<__half, 128, 64, 128, false, false><<<blocks(N, 128), 256, 0, stream>>>(B, W3, P16b, nullptr, N);
        k_agg16s<64, 2, true, false><<<2 * blocks(N, 64), 256, 0, stream>>>(P16b, starts, csr, dinv, b3, H3, N);
        // --- pool + final ---
        k_pool<<<Gn, F3, 0, stream>>>(H3, batch, N, F3, pooled);
    } else {
        k_gemm_naive<<<blocks((long)N * F1, BLK), BLK, 0, stream>>>(x, W1, A, N, K0, F1);
        k_aggregate4<128><<<blocks(N, 8), 256, 0, stream>>>(A, starts, csr, dinv, b1, B, N, 1);
        k_gemm_naive<<<blocks((long)N * F2, BLK), BLK, 0, stream>>>(B, W2, A, N, F1, F2);
        k_aggregate4<128><<<blocks(N, 8), 256, 0, stream>>>(A, starts, csr, dinv, b2, B, N, 1);
        k_gemm_naive<<<blocks((long)N * F3, BLK), BLK, 0, stream>>>(B, W3, A, N, F2, F3);
        k_aggregate4<64><<<blocks(N, 16), 256, 0, stream>>>(A, starts, csr, dinv, b3, B, N, 0);
        k_pool<<<Gn, F3, 0, stream>>>(B, batch, N, F3, pooled);
    }

    k_final<<<blocks(Gn * C, BLK), BLK, 0, stream>>>(pooled, Wl, bl, (float*)d_out, Gn, F3, C);
}

// Round 9
// 250.057 us; speedup vs baseline: 1.5784x; 1.5784x over previous
//
#include <hip/hip_runtime.h>
#include <hip/hip_fp16.h>

typedef _Float16 f16;
typedef f16 f16x8 __attribute__((ext_vector_type(8)));
typedef float f32x4 __attribute__((ext_vector_type(4)));

// ---------------- utility kernels ----------------

__global__ void k_zero_i32(int* __restrict__ p, int n) {
    int i = blockIdx.x * blockDim.x + threadIdx.x;
    if (i < n) p[i] = 0;
}

__global__ void k_count(const int* __restrict__ col, int E, int* __restrict__ cnt) {
    int e = blockIdx.x * blockDim.x + threadIdx.x;
    if (e < E) atomicAdd(&cnt[col[e]], 1);
}

// ---- 3-pass parallel exclusive scan over cnt[0..N) -> starts[0..N] ----
__global__ void k_bsum(const int* __restrict__ cnt, int N, int* __restrict__ bsum) {
    __shared__ int wt[4];
    int t = threadIdx.x;
    int i0 = blockIdx.x * 1024 + t * 4;
    int s = 0;
    #pragma unroll
    for (int j = 0; j < 4; ++j) { int i = i0 + j; if (i < N) s += cnt[i]; }
    #pragma unroll
    for (int off = 32; off > 0; off >>= 1) s += __shfl_down(s, off, 64);
    if ((t & 63) == 0) wt[t >> 6] = s;
    __syncthreads();
    if (t == 0) bsum[blockIdx.x] = wt[0] + wt[1] + wt[2] + wt[3];
}

__global__ void k_bscan(int* __restrict__ bsum, int nb, int* __restrict__ starts, int N) {
    int lane = threadIdx.x;
    int carry = 0;
    for (int base = 0; base < nb; base += 64) {
        int i = base + lane;
        int v = (i < nb) ? bsum[i] : 0;
        int s = v;
        #pragma unroll
        for (int off = 1; off < 64; off <<= 1) {
            int u = __shfl_up(s, off, 64);
            if (lane >= off) s += u;
        }
        if (i < nb) bsum[i] = carry + s - v;
        carry += __shfl(s, 63, 64);
    }
    if (lane == 0) starts[N] = carry;
}

__global__ void k_scan_apply(const int* __restrict__ cnt, const int* __restrict__ bsum,
                             int* __restrict__ starts, int N) {
    __shared__ int wt[4];
    int t = threadIdx.x;
    int lane = t & 63;
    int w = t >> 6;
    int i0 = blockIdx.x * 1024 + t * 4;
    int v[4];
    int ts = 0;
    #pragma unroll
    for (int j = 0; j < 4; ++j) { int i = i0 + j; v[j] = (i < N) ? cnt[i] : 0; ts += v[j]; }
    int s = ts;
    #pragma unroll
    for (int off = 1; off < 64; off <<= 1) {
        int u = __shfl_up(s, off, 64);
        if (lane >= off) s += u;
    }
    if (lane == 63) wt[w] = s;
    __syncthreads();
    int woff = 0;
    if (w > 0) woff = wt[0];
    if (w > 1) woff += wt[1];
    if (w > 2) woff += wt[2];
    int base = bsum[blockIdx.x] + woff + (s - ts);
    int run = base;
    #pragma unroll
    for (int j = 0; j < 4; ++j) { int i = i0 + j; if (i < N) starts[i] = run; run += v[j]; }
}

__global__ void k_dinv(const int* __restrict__ starts, float* __restrict__ dinv, int N) {
    int i = blockIdx.x * blockDim.x + threadIdx.x;
    if (i < N) dinv[i] = rsqrtf((float)(starts[i + 1] - starts[i]) + 1.0f);
}

// XCD-windowed CSR fill (kept from R5/R6: not in top-5 since)
__global__ void k_fill_xcd(const int* __restrict__ row, const int* __restrict__ col, int E,
                           const int* __restrict__ starts, int* __restrict__ cnt,
                           int* __restrict__ csr, int N) {
    const int w = blockIdx.x & 7;
    const int chunk = blockIdx.x >> 3;
    const int nchunks = gridDim.x >> 3;
    const int W = (N + 7) / 8;
    const int c0 = w * W;
    const int c1 = min(N, c0 + W);
    const int stride = nchunks * blockDim.x;
    for (int e = chunk * blockDim.x + threadIdx.x; e < E; e += stride) {
        int c = col[e];
        if (c >= c0 && c < c1) {
            int pos = starts[c] + atomicSub(&cnt[c], 1) - 1;
            csr[pos] = row[e];
        }
    }
}

// x fp32 -> fp16
__global__ void k_f2h(const float* __restrict__ src, __half* __restrict__ dst, long n) {
    long i = ((long)blockIdx.x * blockDim.x + threadIdx.x) * 4;
    if (i + 3 < n) {
        float4 v = *(const float4*)&src[i];
        __half2 h0 = __floats2half2_rn(v.x, v.y);
        __half2 h1 = __floats2half2_rn(v.z, v.w);
        uint2 q; q.x = *(unsigned int*)&h0; q.y = *(unsigned int*)&h1;
        *(uint2*)&dst[i] = q;
    } else {
        for (long j = i; j < n; ++j) dst[j] = __float2half_rn(src[j]);
    }
}

// W[K][M] fp32 -> Wt[m*KP + k] fp16 (transposed, row-padded to KP)
__global__ void k_wprep(const float* __restrict__ W, f16* __restrict__ Wt,
                        int K, int M, int KP) {
    int idx = blockIdx.x * blockDim.x + threadIdx.x;
    if (idx >= K * M) return;
    int k = idx / M;
    int m = idx - k * M;
    Wt[(long)m * KP + k] = (f16)W[idx];
}

// ---------------- MFMA fp16 GEMM ----------------
// P[n][m] = A[n][k] (f16) @ W[k][m] (via Wt[m][k] f16, LDS-staged) [+bias][relu]
// v_mfma_f32_16x16x32_f16 layouts (m89/m101-verified family):
//   A: row=lane&15, k=(lane>>4)*8+j  (8 consecutive f16 -> 16B global load)
//   B: col=lane&15, k=(lane>>4)*8+j  (16B ds_read from Wt row; KP pad -> bank-balanced)
//   D: col=lane&15, row=(lane>>4)*4+reg
// Block = 4 waves x 16 rows = 64 rows; wave loops M/16 col-tiles, K/32 k-steps.

template<int K, int M, bool BIAS, bool RELU, typename OT>
__global__ __launch_bounds__(256) void k_gemm_mfma(const f16* __restrict__ A,
                                                   const f16* __restrict__ Wt,
                                                   const float* __restrict__ bias,
                                                   OT* __restrict__ P, int N) {
    constexpr int KP = K + 8;
    constexpr int KK = K / 32;
    __shared__ f16 Wl[M * KP];
    const int t = threadIdx.x;
    // stage Wt (already transposed+padded in global) -> LDS, straight 16B copy
    constexpr int CH = (M * KP * 2) / 16;
    {
        const uint4* src = (const uint4*)Wt;
        uint4* dst = (uint4*)Wl;
        for (int i = t; i < CH; i += 256) dst[i] = src[i];
    }
    __syncthreads();
    const int lane = t & 63;
    const int wave = t >> 6;
    const int r = lane & 15;       // A row within tile / B,D col within tile
    const int q = lane >> 4;       // k-block / D row-quad
    const int arow = blockIdx.x * 64 + wave * 16 + r;
    f16x8 a[KK];
    #pragma unroll
    for (int kk = 0; kk < KK; ++kk) {
        if (arow < N) a[kk] = *(const f16x8*)&A[(long)arow * K + kk * 32 + q * 8];
        else { f16x8 z = {0, 0, 0, 0, 0, 0, 0, 0}; a[kk] = z; }
    }
    const int drow0 = blockIdx.x * 64 + wave * 16 + q * 4;
    #pragma unroll
    for (int ct = 0; ct < M / 16; ++ct) {
        const int col = ct * 16 + r;
        f32x4 acc = {0.f, 0.f, 0.f, 0.f};
        #pragma unroll
        for (int kk = 0; kk < KK; ++kk) {
            f16x8 b = *(const f16x8*)&Wl[col * KP + kk * 32 + q * 8];
            acc = __builtin_amdgcn_mfma_f32_16x16x32_f16(a[kk], b, acc, 0, 0, 0);
        }
        float bb = BIAS ? bias[col] : 0.f;
        #pragma unroll
        for (int g = 0; g < 4; ++g) {
            int rr = drow0 + g;
            if (rr < N) {
                float v = acc[g] + bb;
                if (RELU) v = fmaxf(v, 0.f);
                if constexpr (__is_same(OT, f16)) P[(long)rr * M + col] = (f16)v;
                else P[(long)rr * M + col] = v;
            }
        }
    }
}

// ---------------- fp16-gather aggregation (R6 full-row design) ----------------
// H[c,f] = relu?( dinv[c]*sum_{r} P16[r,f]*dinv[r] + dinv[c]^2*P16[c,f] (+ b[f]) )

template<int M, bool BIAS, bool RELU, typename OT>
__global__ void k_agg16(const __half* __restrict__ P16, const int* __restrict__ starts,
                        const int* __restrict__ csr, const float* __restrict__ dinv,
                        const float* __restrict__ b, OT* __restrict__ H, int N) {
    constexpr int TPN = M / 8;
    constexpr int NPB = 256 / TPN;
    int local = threadIdx.x / TPN;
    int fq = threadIdx.x % TPN;
    int f0 = fq * 8;
    int c = blockIdx.x * NPB + local;
    if (c >= N) return;
    int s = starts[c], e = starts[c + 1];
    float acc[8] = {};
    int i = s;
    for (; i + 1 < e; i += 2) {
        int r0 = csr[i], r1 = csr[i + 1];
        float d0 = dinv[r0], d1 = dinv[r1];
        uint4 u0 = *(const uint4*)&P16[(long)r0 * M + f0];
        uint4 u1 = *(const uint4*)&P16[(long)r1 * M + f0];
        const __half2* h0 = (const __half2*)&u0;
        const __half2* h1 = (const __half2*)&u1;
        #pragma unroll
        for (int j = 0; j < 4; ++j) {
            float2 f0v = __half22float2(h0[j]);
            float2 f1v = __half22float2(h1[j]);
            acc[2 * j]     += f0v.x * d0 + f1v.x * d1;
            acc[2 * j + 1] += f0v.y * d0 + f1v.y * d1;
        }
    }
    if (i < e) {
        int r0 = csr[i];
        float d0 = dinv[r0];
        uint4 u0 = *(const uint4*)&P16[(long)r0 * M + f0];
        const __half2* h0 = (const __half2*)&u0;
        #pragma unroll
        for (int j = 0; j < 4; ++j) {
            float2 f0v = __half22float2(h0[j]);
            acc[2 * j]     += f0v.x * d0;
            acc[2 * j + 1] += f0v.y * d0;
        }
    }
    float dc = dinv[c];
    float dc2 = dc * dc;
    uint4 us = *(const uint4*)&P16[(long)c * M + f0];
    const __half2* hs = (const __half2*)&us;
    float v[8];
    #pragma unroll
    for (int j = 0; j < 4; ++j) {
        float2 fs = __half22float2(hs[j]);
        v[2 * j]     = dc * acc[2 * j]     + dc2 * fs.x;
        v[2 * j + 1] = dc * acc[2 * j + 1] + dc2 * fs.y;
    }
    if (BIAS) {
        float4 bb0 = *(const float4*)&b[f0];
        float4 bb1 = *(const float4*)&b[f0 + 4];
        v[0] += bb0.x; v[1] += bb0.y; v[2] += bb0.z; v[3] += bb0.w;
        v[4] += bb1.x; v[5] += bb1.y; v[6] += bb1.z; v[7] += bb1.w;
    }
    if (RELU) {
        #pragma unroll
        for (int j = 0; j < 8; ++j) v[j] = fmaxf(v[j], 0.f);
    }
    if constexpr (__is_same(OT, __half)) {
        __half2 h0 = __floats2half2_rn(v[0], v[1]);
        __half2 h1 = __floats2half2_rn(v[2], v[3]);
        __half2 h2 = __floats2half2_rn(v[4], v[5]);
        __half2 h3 = __floats2half2_rn(v[6], v[7]);
        uint4 qo;
        qo.x = *(unsigned int*)&h0; qo.y = *(unsigned int*)&h1;
        qo.z = *(unsigned int*)&h2; qo.w = *(unsigned int*)&h3;
        *(uint4*)&H[(long)c * M + f0] = qo;
    } else {
        *(float4*)&H[(long)c * M + f0]     = make_float4(v[0], v[1], v[2], v[3]);
        *(float4*)&H[(long)c * M + f0 + 4] = make_float4(v[4], v[5], v[6], v[7]);
    }
}

// ---------------- fp32 fallback kernels (unexpected shapes) ----------------

__global__ void k_gemm_naive(const float* __restrict__ X, const float* __restrict__ W,
                             float* __restrict__ P, int N, int K, int M) {
    long idx = (long)blockIdx.x * blockDim.x + threadIdx.x;
    long total = (long)N * M;
    if (idx >= total) return;
    int n = (int)(idx / M);
    int m = (int)(idx - (long)n * M);
    const float* xr = X + (long)n * K;
    float acc = 0.0f;
    for (int k = 0; k < K; ++k) acc += xr[k] * W[k * M + m];
    P[idx] = acc;
}

template<int M>
__global__ void k_aggregate4(const float* __restrict__ P, const int* __restrict__ starts,
                             const int* __restrict__ csr, const float* __restrict__ dinv,
                             const float* __restrict__ b, float* __restrict__ H,
                             int N, int do_relu) {
    constexpr int TPN = M / 4;
    constexpr int NPB = 256 / TPN;
    int local = threadIdx.x / TPN;
    int fq = threadIdx.x % TPN;
    int c = blockIdx.x * NPB + local;
    if (c >= N) return;
    int s = starts[c], e = starts[c + 1];
    float4 acc = make_float4(0.f, 0.f, 0.f, 0.f);
    for (int i = s; i < e; ++i) {
        int r = csr[i];
        float dr = dinv[r];
        float4 p = *(const float4*)&P[(long)r * M + fq * 4];
        acc.x += p.x * dr; acc.y += p.y * dr; acc.z += p.z * dr; acc.w += p.w * dr;
    }
    float dc = dinv[c];
    float dc2 = dc * dc;
    float4 ps = *(const float4*)&P[(long)c * M + fq * 4];
    float4 bb = *(const float4*)&b[fq * 4];
    float4 v;
    v.x = dc * acc.x + dc2 * ps.x + bb.x;
    v.y = dc * acc.y + dc2 * ps.y + bb.y;
    v.z = dc * acc.z + dc2 * ps.z + bb.z;
    v.w = dc * acc.w + dc2 * ps.w + bb.w;
    if (do_relu) {
        v.x = fmaxf(v.x, 0.f); v.y = fmaxf(v.y, 0.f);
        v.z = fmaxf(v.z, 0.f); v.w = fmaxf(v.w, 0.f);
    }
    *(float4*)&H[(long)c * M + fq * 4] = v;
}

// ---------------- pooling + classifier ----------------

__device__ __forceinline__ int lower_bound_i(const int* __restrict__ a, int n, int key) {
    int lo = 0, hi = n;
    while (lo < hi) { int mid = (lo + hi) >> 1; if (a[mid] < key) lo = mid + 1; else hi = mid; }
    return lo;
}

__global__ void k_pool(const float* __restrict__ H, const int* __restrict__ batch,
                       int N, int M, float* __restrict__ pooled) {
    int g = blockIdx.x;
    int f = threadIdx.x;       // blockDim.x == M
    int lo = lower_bound_i(batch, N, g);
    int hi = lower_bound_i(batch, N, g + 1);
    float acc = 0.0f;
    for (int n = lo; n < hi; ++n) acc += H[(long)n * M + f];
    float inv = 1.0f / fmaxf((float)(hi - lo), 1.0f);
    pooled[(long)g * M + f] = acc * inv;
}

__global__ void k_final(const float* __restrict__ pooled, const float* __restrict__ Wl,
                        const float* __restrict__ bl, float* __restrict__ out,
                        int Gn, int F, int C) {
    int idx = blockIdx.x * blockDim.x + threadIdx.x;
    if (idx >= Gn * C) return;
    int g = idx / C;
    int j = idx - g * C;
    float acc = bl[j];
    for (int f = 0; f < F; ++f) acc += pooled[g * F + f] * Wl[f * C + j];
    out[idx] = acc;
}

// ---------------- launch ----------------

extern "C" void kernel_launch(void* const* d_in, const int* in_sizes, int n_in,
                              void* d_out, int out_size, void* d_ws, size_t ws_size,
                              hipStream_t stream) {
    const float* x  = (const float*)d_in[0];
    const int*   ei = (const int*)d_in[1];
    const int*   batch = (const int*)d_in[2];
    const float* W1 = (const float*)d_in[3];
    const float* b1 = (const float*)d_in[4];
    const float* W2 = (const float*)d_in[5];
    const float* b2 = (const float*)d_in[6];
    const float* W3 = (const float*)d_in[7];
    const float* b3 = (const float*)d_in[8];
    const float* Wl = (const float*)d_in[9];
    const float* bl = (const float*)d_in[10];

    const int N  = in_sizes[2];          // 50000
    const int E  = in_sizes[1] / 2;      // 800000
    const int C  = in_sizes[10];         // 10
    const int Gn = out_size / C;         // 512
    const int F1 = in_sizes[4];          // 128
    const int F2 = in_sizes[6];          // 128
    const int F3 = in_sizes[8];          // 64
    const int K0 = in_sizes[0] / N;      // 64

    const int* row = ei;
    const int* col = ei + E;

    // workspace layout (64B-aligned chunks)
    char* base = (char*)d_ws;
    size_t off = 0;
    auto alloc = [&](size_t bytes) {
        off = (off + 63) & ~(size_t)63;
        void* p = base + off;
        off += bytes;
        return p;
    };
    int* cnt     = (int*)alloc((size_t)N * 4);
    int* starts  = (int*)alloc((size_t)(N + 1) * 4);
    int* bsum    = (int*)alloc(256 * 4);
    int* csr     = (int*)alloc((size_t)E * 4);
    float* dinv  = (float*)alloc((size_t)N * 4);
    __half* X16  = (__half*)alloc((size_t)N * 64 * 2);
    __half* AX16 = (__half*)alloc((size_t)N * 64 * 2);
    __half* H1   = (__half*)alloc((size_t)N * 128 * 2);
    __half* P16a = (__half*)alloc((size_t)N * 128 * 2);
    __half* B16  = (__half*)alloc((size_t)N * 128 * 2);
    __half* P16b = (__half*)alloc((size_t)N * 64 * 2);
    float* H3    = (float*)alloc((size_t)N * 64 * 4);
    f16* Wt1     = (f16*)alloc((size_t)128 * 72 * 2);    // [M=128][KP=72]
    f16* Wt2     = (f16*)alloc((size_t)128 * 136 * 2);   // [M=128][KP=136]
    f16* Wt3     = (f16*)alloc((size_t)64 * 136 * 2);    // [M=64][KP=136]
    float* pooled = (float*)alloc((size_t)Gn * 64 * 4);
    float* Afb   = (float*)alloc((size_t)N * 128 * 4);   // fallback only
    float* Bfb   = (float*)alloc((size_t)N * 128 * 4);   // fallback only

    const int BLK = 256;
    auto blocks = [](long n, int b) { return (int)((n + b - 1) / b); };
    const int nb = blocks(N, 1024);

    // --- build CSR ---
    k_zero_i32<<<blocks(N, BLK), BLK, 0, stream>>>(cnt, N);
    k_count<<<blocks(E, BLK), BLK, 0, stream>>>(col, E, cnt);
    k_bsum<<<nb, 256, 0, stream>>>(cnt, N, bsum);
    k_bscan<<<1, 64, 0, stream>>>(bsum, nb, starts, N);
    k_scan_apply<<<nb, 256, 0, stream>>>(cnt, bsum, starts, N);
    k_dinv<<<blocks(N, BLK), BLK, 0, stream>>>(starts, dinv, N);
    k_fill_xcd<<<128 * 8, 256, 0, stream>>>(row, col, E, starts, cnt, csr, N);

    const bool fast = (K0 == 64 && F1 == 128 && F2 == 128 && F3 == 64);

    if (fast) {
        // weight prep (fp16, transposed, padded)
        k_f2h<<<blocks(((long)N * 64 + 3) / 4, BLK), BLK, 0, stream>>>(x, X16, (long)N * 64);
        k_wprep<<<blocks(64 * 128, BLK), BLK, 0, stream>>>(W1, Wt1, 64, 128, 72);
        k_wprep<<<blocks(128 * 128, BLK), BLK, 0, stream>>>(W2, Wt2, 128, 128, 136);
        k_wprep<<<blocks(128 * 64, BLK), BLK, 0, stream>>>(W3, Wt3, 128, 64, 136);

        // layer 1 (reordered): H1 = relu( (A_hat X) W1 + b1 )
        k_agg16<64, false, false, __half><<<blocks(N, 32), 256, 0, stream>>>(X16, starts, csr, dinv, nullptr, AX16, N);
        k_gemm_mfma<64, 128, true, true, f16><<<blocks(N, 64), 256, 0, stream>>>((const f16*)AX16, Wt1, b1, (f16*)H1, N);
        // layer 2: B16 = relu( A_hat (H1 W2) + b2 )
        k_gemm_mfma<128, 128, false, false, f16><<<blocks(N, 64), 256, 0, stream>>>((const f16*)H1, Wt2, nullptr, (f16*)P16a, N);
        k_agg16<128, true, true, __half><<<blocks(N, 16), 256, 0, stream>>>(P16a, starts, csr, dinv, b2, B16, N);
        // layer 3: H3 = A_hat (B16 W3) + b3
        k_gemm_mfma<128, 64, false, false, f16><<<blocks(N, 64), 256, 0, stream>>>((const f16*)B16, Wt3, nullptr, (f16*)P16b, N);
        k_agg16<64, true, false, float><<<blocks(N, 32), 256, 0, stream>>>(P16b, starts, csr, dinv, b3, H3, N);
        // pool + final
        k_pool<<<Gn, F3, 0, stream>>>(H3, batch, N, F3, pooled);
    } else {
        k_gemm_naive<<<blocks((long)N * F1, BLK), BLK, 0, stream>>>(x, W1, Afb, N, K0, F1);
        k_aggregate4<128><<<blocks(N, 8), 256, 0, stream>>>(Afb, starts, csr, dinv, b1, Bfb, N, 1);
        k_gemm_naive<<<blocks((long)N * F2, BLK), BLK, 0, stream>>>(Bfb, W2, Afb, N, F1, F2);
        k_aggregate4<128><<<blocks(N, 8), 256, 0, stream>>>(Afb, starts, csr, dinv, b2, Bfb, N, 1);
        k_gemm_naive<<<blocks((long)N * F3, BLK), BLK, 0, stream>>>(Bfb, W3, Afb, N, F2, F3);
        k_aggregate4<64><<<blocks(N, 16), 256, 0, stream>>>(Afb, starts, csr, dinv, b3, Bfb, N, 0);
        k_pool<<<Gn, F3, 0, stream>>>(Bfb, batch, N, F3, pooled);
    }

    k_final<<<blocks(Gn * C, BLK), BLK, 0, stream>>>(pooled, Wl, bl, (float*)d_out, Gn, F3, C);
}

// Round 10
// 231.431 us; speedup vs baseline: 1.7054x; 1.0805x over previous
//
#include <hip/hip_runtime.h>
#include <hip/hip_fp16.h>

typedef _Float16 f16;
typedef f16 f16x8 __attribute__((ext_vector_type(8)));
typedef float f32x4 __attribute__((ext_vector_type(4)));

// ---------------- utility kernels ----------------

__global__ void k_zero_i32(int* __restrict__ p, int n) {
    int i = blockIdx.x * blockDim.x + threadIdx.x;
    if (i < n) p[i] = 0;
}

__global__ void k_count(const int* __restrict__ col, int E, int* __restrict__ cnt) {
    int e = blockIdx.x * blockDim.x + threadIdx.x;
    if (e < E) atomicAdd(&cnt[col[e]], 1);
}

// ---- 3-pass parallel exclusive scan over cnt[0..N) -> starts[0..N] ----
__global__ void k_bsum(const int* __restrict__ cnt, int N, int* __restrict__ bsum) {
    __shared__ int wt[4];
    int t = threadIdx.x;
    int i0 = blockIdx.x * 1024 + t * 4;
    int s = 0;
    #pragma unroll
    for (int j = 0; j < 4; ++j) { int i = i0 + j; if (i < N) s += cnt[i]; }
    #pragma unroll
    for (int off = 32; off > 0; off >>= 1) s += __shfl_down(s, off, 64);
    if ((t & 63) == 0) wt[t >> 6] = s;
    __syncthreads();
    if (t == 0) bsum[blockIdx.x] = wt[0] + wt[1] + wt[2] + wt[3];
}

__global__ void k_bscan(int* __restrict__ bsum, int nb, int* __restrict__ starts, int N) {
    int lane = threadIdx.x;
    int carry = 0;
    for (int base = 0; base < nb; base += 64) {
        int i = base + lane;
        int v = (i < nb) ? bsum[i] : 0;
        int s = v;
        #pragma unroll
        for (int off = 1; off < 64; off <<= 1) {
            int u = __shfl_up(s, off, 64);
            if (lane >= off) s += u;
        }
        if (i < nb) bsum[i] = carry + s - v;
        carry += __shfl(s, 63, 64);
    }
    if (lane == 0) starts[N] = carry;
}

// pass 3 (+fused dinv): rescan chunk + chunk offset -> exclusive starts; dinv from cnt
__global__ void k_scan_apply(const int* __restrict__ cnt, const int* __restrict__ bsum,
                             int* __restrict__ starts, float* __restrict__ dinv, int N) {
    __shared__ int wt[4];
    int t = threadIdx.x;
    int lane = t & 63;
    int w = t >> 6;
    int i0 = blockIdx.x * 1024 + t * 4;
    int v[4];
    int ts = 0;
    #pragma unroll
    for (int j = 0; j < 4; ++j) { int i = i0 + j; v[j] = (i < N) ? cnt[i] : 0; ts += v[j]; }
    int s = ts;
    #pragma unroll
    for (int off = 1; off < 64; off <<= 1) {
        int u = __shfl_up(s, off, 64);
        if (lane >= off) s += u;
    }
    if (lane == 63) wt[w] = s;
    __syncthreads();
    int woff = 0;
    if (w > 0) woff = wt[0];
    if (w > 1) woff += wt[1];
    if (w > 2) woff += wt[2];
    int base = bsum[blockIdx.x] + woff + (s - ts);
    int run = base;
    #pragma unroll
    for (int j = 0; j < 4; ++j) {
        int i = i0 + j;
        if (i < N) {
            starts[i] = run;
            dinv[i] = rsqrtf((float)v[j] + 1.0f);
        }
        run += v[j];
    }
}

// XCD-windowed CSR fill
__global__ void k_fill_xcd(const int* __restrict__ row, const int* __restrict__ col, int E,
                           const int* __restrict__ starts, int* __restrict__ cnt,
                           int* __restrict__ csr, int N) {
    const int w = blockIdx.x & 7;
    const int chunk = blockIdx.x >> 3;
    const int nchunks = gridDim.x >> 3;
    const int W = (N + 7) / 8;
    const int c0 = w * W;
    const int c1 = min(N, c0 + W);
    const int stride = nchunks * blockDim.x;
    for (int e = chunk * blockDim.x + threadIdx.x; e < E; e += stride) {
        int c = col[e];
        if (c >= c0 && c < c1) {
            int pos = starts[c] + atomicSub(&cnt[c], 1) - 1;
            csr[pos] = row[e];
        }
    }
}

// x fp32 -> fp16
__global__ void k_f2h(const float* __restrict__ src, __half* __restrict__ dst, long n) {
    long i = ((long)blockIdx.x * blockDim.x + threadIdx.x) * 4;
    if (i + 3 < n) {
        float4 v = *(const float4*)&src[i];
        __half2 h0 = __floats2half2_rn(v.x, v.y);
        __half2 h1 = __floats2half2_rn(v.z, v.w);
        uint2 q; q.x = *(unsigned int*)&h0; q.y = *(unsigned int*)&h1;
        *(uint2*)&dst[i] = q;
    } else {
        for (long j = i; j < n; ++j) dst[j] = __float2half_rn(src[j]);
    }
}

// all three weights: W[K][M] fp32 -> Wt[m*KP + k] fp16 (transposed, padded)
__global__ void k_wprep3(const float* __restrict__ W1, const float* __restrict__ W2,
                         const float* __restrict__ W3, f16* __restrict__ Wt1,
                         f16* __restrict__ Wt2, f16* __restrict__ Wt3) {
    int idx = blockIdx.x * blockDim.x + threadIdx.x;
    if (idx < 8192) {                      // W1: 64x128 -> [128][72]
        int k = idx >> 7, m = idx & 127;
        Wt1[m * 72 + k] = (f16)W1[idx];
    } else if (idx < 24576) {              // W2: 128x128 -> [128][136]
        int j = idx - 8192;
        int k = j >> 7, m = j & 127;
        Wt2[m * 136 + k] = (f16)W2[j];
    } else if (idx < 32768) {              // W3: 128x64 -> [64][136]
        int j = idx - 24576;
        int k = j >> 6, m = j & 63;
        Wt3[m * 136 + k] = (f16)W3[j];
    }
}

// ---------------- MFMA fp16 GEMM (R8 design, unchanged) ----------------

template<int K, int M, bool BIAS, bool RELU, typename OT>
__global__ __launch_bounds__(256) void k_gemm_mfma(const f16* __restrict__ A,
                                                   const f16* __restrict__ Wt,
                                                   const float* __restrict__ bias,
                                                   OT* __restrict__ P, int N) {
    constexpr int KP = K + 8;
    constexpr int KK = K / 32;
    __shared__ f16 Wl[M * KP];
    const int t = threadIdx.x;
    constexpr int CH = (M * KP * 2) / 16;
    {
        const uint4* src = (const uint4*)Wt;
        uint4* dst = (uint4*)Wl;
        for (int i = t; i < CH; i += 256) dst[i] = src[i];
    }
    __syncthreads();
    const int lane = t & 63;
    const int wave = t >> 6;
    const int r = lane & 15;
    const int q = lane >> 4;
    const int arow = blockIdx.x * 64 + wave * 16 + r;
    f16x8 a[KK];
    #pragma unroll
    for (int kk = 0; kk < KK; ++kk) {
        if (arow < N) a[kk] = *(const f16x8*)&A[(long)arow * K + kk * 32 + q * 8];
        else { f16x8 z = {0, 0, 0, 0, 0, 0, 0, 0}; a[kk] = z; }
    }
    const int drow0 = blockIdx.x * 64 + wave * 16 + q * 4;
    #pragma unroll
    for (int ct = 0; ct < M / 16; ++ct) {
        const int col = ct * 16 + r;
        f32x4 acc = {0.f, 0.f, 0.f, 0.f};
        #pragma unroll
        for (int kk = 0; kk < KK; ++kk) {
            f16x8 b = *(const f16x8*)&Wl[col * KP + kk * 32 + q * 8];
            acc = __builtin_amdgcn_mfma_f32_16x16x32_f16(a[kk], b, acc, 0, 0, 0);
        }
        float bb = BIAS ? bias[col] : 0.f;
        #pragma unroll
        for (int g = 0; g < 4; ++g) {
            int rr = drow0 + g;
            if (rr < N) {
                float v = acc[g] + bb;
                if (RELU) v = fmaxf(v, 0.f);
                if constexpr (__is_same(OT, f16)) P[(long)rr * M + col] = (f16)v;
                else P[(long)rr * M + col] = v;
            }
        }
    }
}

// ---------------- fp16-gather aggregation, 4-wide neighbor unroll ----------------

template<int M, bool BIAS, bool RELU, typename OT>
__global__ void k_agg16(const __half* __restrict__ P16, const int* __restrict__ starts,
                        const int* __restrict__ csr, const float* __restrict__ dinv,
                        const float* __restrict__ b, OT* __restrict__ H, int N) {
    constexpr int TPN = M / 8;
    constexpr int NPB = 256 / TPN;
    int local = threadIdx.x / TPN;
    int fq = threadIdx.x % TPN;
    int f0 = fq * 8;
    int c = blockIdx.x * NPB + local;
    if (c >= N) return;
    int s = starts[c], e = starts[c + 1];
    float acc[8] = {};
    int i = s;
    for (; i + 3 < e; i += 4) {
        int r0 = csr[i], r1 = csr[i + 1], r2 = csr[i + 2], r3 = csr[i + 3];
        float d0 = dinv[r0], d1 = dinv[r1], d2 = dinv[r2], d3 = dinv[r3];
        uint4 u0 = *(const uint4*)&P16[(long)r0 * M + f0];
        uint4 u1 = *(const uint4*)&P16[(long)r1 * M + f0];
        uint4 u2 = *(const uint4*)&P16[(long)r2 * M + f0];
        uint4 u3 = *(const uint4*)&P16[(long)r3 * M + f0];
        const __half2* h0 = (const __half2*)&u0;
        const __half2* h1 = (const __half2*)&u1;
        const __half2* h2 = (const __half2*)&u2;
        const __half2* h3 = (const __half2*)&u3;
        #pragma unroll
        for (int j = 0; j < 4; ++j) {
            float2 v0 = __half22float2(h0[j]);
            float2 v1 = __half22float2(h1[j]);
            float2 v2 = __half22float2(h2[j]);
            float2 v3 = __half22float2(h3[j]);
            acc[2 * j]     += v0.x * d0 + v1.x * d1 + v2.x * d2 + v3.x * d3;
            acc[2 * j + 1] += v0.y * d0 + v1.y * d1 + v2.y * d2 + v3.y * d3;
        }
    }
    for (; i < e; ++i) {
        int r0 = csr[i];
        float d0 = dinv[r0];
        uint4 u0 = *(const uint4*)&P16[(long)r0 * M + f0];
        const __half2* h0 = (const __half2*)&u0;
        #pragma unroll
        for (int j = 0; j < 4; ++j) {
            float2 v0 = __half22float2(h0[j]);
            acc[2 * j]     += v0.x * d0;
            acc[2 * j + 1] += v0.y * d0;
        }
    }
    float dc = dinv[c];
    float dc2 = dc * dc;
    uint4 us = *(const uint4*)&P16[(long)c * M + f0];
    const __half2* hs = (const __half2*)&us;
    float v[8];
    #pragma unroll
    for (int j = 0; j < 4; ++j) {
        float2 fs = __half22float2(hs[j]);
        v[2 * j]     = dc * acc[2 * j]     + dc2 * fs.x;
        v[2 * j + 1] = dc * acc[2 * j + 1] + dc2 * fs.y;
    }
    if (BIAS) {
        float4 bb0 = *(const float4*)&b[f0];
        float4 bb1 = *(const float4*)&b[f0 + 4];
        v[0] += bb0.x; v[1] += bb0.y; v[2] += bb0.z; v[3] += bb0.w;
        v[4] += bb1.x; v[5] += bb1.y; v[6] += bb1.z; v[7] += bb1.w;
    }
    if (RELU) {
        #pragma unroll
        for (int j = 0; j < 8; ++j) v[j] = fmaxf(v[j], 0.f);
    }
    if constexpr (__is_same(OT, __half)) {
        __half2 h0 = __floats2half2_rn(v[0], v[1]);
        __half2 h1 = __floats2half2_rn(v[2], v[3]);
        __half2 h2 = __floats2half2_rn(v[4], v[5]);
        __half2 h3 = __floats2half2_rn(v[6], v[7]);
        uint4 qo;
        qo.x = *(unsigned int*)&h0; qo.y = *(unsigned int*)&h1;
        qo.z = *(unsigned int*)&h2; qo.w = *(unsigned int*)&h3;
        *(uint4*)&H[(long)c * M + f0] = qo;
    } else {
        *(float4*)&H[(long)c * M + f0]     = make_float4(v[0], v[1], v[2], v[3]);
        *(float4*)&H[(long)c * M + f0 + 4] = make_float4(v[4], v[5], v[6], v[7]);
    }
}

// ---------------- fp32 fallback kernels (unexpected shapes) ----------------

__global__ void k_gemm_naive(const float* __restrict__ X, const float* __restrict__ W,
                             float* __restrict__ P, int N, int K, int M) {
    long idx = (long)blockIdx.x * blockDim.x + threadIdx.x;
    long total = (long)N * M;
    if (idx >= total) return;
    int n = (int)(idx / M);
    int m = (int)(idx - (long)n * M);
    const float* xr = X + (long)n * K;
    float acc = 0.0f;
    for (int k = 0; k < K; ++k) acc += xr[k] * W[k * M + m];
    P[idx] = acc;
}

template<int M>
__global__ void k_aggregate4(const float* __restrict__ P, const int* __restrict__ starts,
                             const int* __restrict__ csr, const float* __restrict__ dinv,
                             const float* __restrict__ b, float* __restrict__ H,
                             int N, int do_relu) {
    constexpr int TPN = M / 4;
    constexpr int NPB = 256 / TPN;
    int local = threadIdx.x / TPN;
    int fq = threadIdx.x % TPN;
    int c = blockIdx.x * NPB + local;
    if (c >= N) return;
    int s = starts[c], e = starts[c + 1];
    float4 acc = make_float4(0.f, 0.f, 0.f, 0.f);
    for (int i = s; i < e; ++i) {
        int r = csr[i];
        float dr = dinv[r];
        float4 p = *(const float4*)&P[(long)r * M + fq * 4];
        acc.x += p.x * dr; acc.y += p.y * dr; acc.z += p.z * dr; acc.w += p.w * dr;
    }
    float dc = dinv[c];
    float dc2 = dc * dc;
    float4 ps = *(const float4*)&P[(long)c * M + fq * 4];
    float4 bb = *(const float4*)&b[fq * 4];
    float4 v;
    v.x = dc * acc.x + dc2 * ps.x + bb.x;
    v.y = dc * acc.y + dc2 * ps.y + bb.y;
    v.z = dc * acc.z + dc2 * ps.z + bb.z;
    v.w = dc * acc.w + dc2 * ps.w + bb.w;
    if (do_relu) {
        v.x = fmaxf(v.x, 0.f); v.y = fmaxf(v.y, 0.f);
        v.z = fmaxf(v.z, 0.f); v.w = fmaxf(v.w, 0.f);
    }
    *(float4*)&H[(long)c * M + fq * 4] = v;
}

// ---------------- pooling + classifier ----------------

__device__ __forceinline__ int lower_bound_i(const int* __restrict__ a, int n, int key) {
    int lo = 0, hi = n;
    while (lo < hi) { int mid = (lo + hi) >> 1; if (a[mid] < key) lo = mid + 1; else hi = mid; }
    return lo;
}

// fused mean-pool + final linear; one 64-thread block per graph (M == 64)
__global__ void k_poolfinal(const float* __restrict__ H, const int* __restrict__ batch,
                            int N, const float* __restrict__ Wl,
                            const float* __restrict__ bl, float* __restrict__ out, int C) {
    __shared__ float pl[64];
    int g = blockIdx.x;
    int f = threadIdx.x;     // 64 threads
    int lo = lower_bound_i(batch, N, g);
    int hi = lower_bound_i(batch, N, g + 1);
    float acc = 0.0f;
    for (int n = lo; n < hi; ++n) acc += H[(long)n * 64 + f];
    pl[f] = acc / fmaxf((float)(hi - lo), 1.0f);
    __syncthreads();
    if (f < C) {
        float o = bl[f];
        #pragma unroll 8
        for (int k = 0; k < 64; ++k) o += pl[k] * Wl[k * C + f];
        out[g * C + f] = o;
    }
}

__global__ void k_pool(const float* __restrict__ H, const int* __restrict__ batch,
                       int N, int M, float* __restrict__ pooled) {
    int g = blockIdx.x;
    int f = threadIdx.x;
    int lo = lower_bound_i(batch, N, g);
    int hi = lower_bound_i(batch, N, g + 1);
    float acc = 0.0f;
    for (int n = lo; n < hi; ++n) acc += H[(long)n * M + f];
    float inv = 1.0f / fmaxf((float)(hi - lo), 1.0f);
    pooled[(long)g * M + f] = acc * inv;
}

__global__ void k_final(const float* __restrict__ pooled, const float* __restrict__ Wl,
                        const float* __restrict__ bl, float* __restrict__ out,
                        int Gn, int F, int C) {
    int idx = blockIdx.x * blockDim.x + threadIdx.x;
    if (idx >= Gn * C) return;
    int g = idx / C;
    int j = idx - g * C;
    float acc = bl[j];
    for (int f = 0; f < F; ++f) acc += pooled[g * F + f] * Wl[f * C + j];
    out[idx] = acc;
}

// ---------------- launch ----------------

extern "C" void kernel_launch(void* const* d_in, const int* in_sizes, int n_in,
                              void* d_out, int out_size, void* d_ws, size_t ws_size,
                              hipStream_t stream) {
    const float* x  = (const float*)d_in[0];
    const int*   ei = (const int*)d_in[1];
    const int*   batch = (const int*)d_in[2];
    const float* W1 = (const float*)d_in[3];
    const float* b1 = (const float*)d_in[4];
    const float* W2 = (const float*)d_in[5];
    const float* b2 = (const float*)d_in[6];
    const float* W3 = (const float*)d_in[7];
    const float* b3 = (const float*)d_in[8];
    const float* Wl = (const float*)d_in[9];
    const float* bl = (const float*)d_in[10];

    const int N  = in_sizes[2];          // 50000
    const int E  = in_sizes[1] / 2;      // 800000
    const int C  = in_sizes[10];         // 10
    const int Gn = out_size / C;         // 512
    const int F1 = in_sizes[4];          // 128
    const int F2 = in_sizes[6];          // 128
    const int F3 = in_sizes[8];          // 64
    const int K0 = in_sizes[0] / N;      // 64

    const int* row = ei;
    const int* col = ei + E;

    // workspace layout (64B-aligned chunks)
    char* base = (char*)d_ws;
    size_t off = 0;
    auto alloc = [&](size_t bytes) {
        off = (off + 63) & ~(size_t)63;
        void* p = base + off;
        off += bytes;
        return p;
    };
    int* cnt     = (int*)alloc((size_t)N * 4);
    int* starts  = (int*)alloc((size_t)(N + 1) * 4);
    int* bsum    = (int*)alloc(256 * 4);
    int* csr     = (int*)alloc((size_t)E * 4);
    float* dinv  = (float*)alloc((size_t)N * 4);
    __half* X16  = (__half*)alloc((size_t)N * 64 * 2);
    __half* AX16 = (__half*)alloc((size_t)N * 64 * 2);
    __half* H1   = (__half*)alloc((size_t)N * 128 * 2);
    __half* P16a = (__half*)alloc((size_t)N * 128 * 2);
    __half* B16  = (__half*)alloc((size_t)N * 128 * 2);
    __half* P16b = (__half*)alloc((size_t)N * 64 * 2);
    float* H3    = (float*)alloc((size_t)N * 64 * 4);
    f16* Wt1     = (f16*)alloc((size_t)128 * 72 * 2);
    f16* Wt2     = (f16*)alloc((size_t)128 * 136 * 2);
    f16* Wt3     = (f16*)alloc((size_t)64 * 136 * 2);
    float* pooled = (float*)alloc((size_t)Gn * 64 * 4);
    float* Afb   = (float*)alloc((size_t)N * 128 * 4);
    float* Bfb   = (float*)alloc((size_t)N * 128 * 4);

    const int BLK = 256;
    auto blocks = [](long n, int b) { return (int)((n + b - 1) / b); };
    const int nb = blocks(N, 1024);

    // --- build CSR (+ dinv fused into scan_apply) ---
    k_zero_i32<<<blocks(N, BLK), BLK, 0, stream>>>(cnt, N);
    k_count<<<blocks(E, BLK), BLK, 0, stream>>>(col, E, cnt);
    k_bsum<<<nb, 256, 0, stream>>>(cnt, N, bsum);
    k_bscan<<<1, 64, 0, stream>>>(bsum, nb, starts, N);
    k_scan_apply<<<nb, 256, 0, stream>>>(cnt, bsum, starts, dinv, N);
    k_fill_xcd<<<128 * 8, 256, 0, stream>>>(row, col, E, starts, cnt, csr, N);

    const bool fast = (K0 == 64 && F1 == 128 && F2 == 128 && F3 == 64);

    if (fast) {
        k_f2h<<<blocks(((long)N * 64 + 3) / 4, BLK), BLK, 0, stream>>>(x, X16, (long)N * 64);
        k_wprep3<<<128, 256, 0, stream>>>(W1, W2, W3, Wt1, Wt2, Wt3);

        // layer 1 (reordered): H1 = relu( (A_hat X) W1 + b1 )
        k_agg16<64, false, false, __half><<<blocks(N, 32), 256, 0, stream>>>(X16, starts, csr, dinv, nullptr, AX16, N);
        k_gemm_mfma<64, 128, true, true, f16><<<blocks(N, 64), 256, 0, stream>>>((const f16*)AX16, Wt1, b1, (f16*)H1, N);
        // layer 2: B16 = relu( A_hat (H1 W2) + b2 )
        k_gemm_mfma<128, 128, false, false, f16><<<blocks(N, 64), 256, 0, stream>>>((const f16*)H1, Wt2, nullptr, (f16*)P16a, N);
        k_agg16<128, true, true, __half><<<blocks(N, 16), 256, 0, stream>>>(P16a, starts, csr, dinv, b2, B16, N);
        // layer 3: H3 = A_hat (B16 W3) + b3
        k_gemm_mfma<128, 64, false, false, f16><<<blocks(N, 64), 256, 0, stream>>>((const f16*)B16, Wt3, nullptr, (f16*)P16b, N);
        k_agg16<64, true, false, float><<<blocks(N, 32), 256, 0, stream>>>(P16b, starts, csr, dinv, b3, H3, N);
        // fused pool + classifier
        k_poolfinal<<<Gn, 64, 0, stream>>>(H3, batch, N, Wl, bl, (float*)d_out, C);
    } else {
        k_gemm_naive<<<blocks((long)N * F1, BLK), BLK, 0, stream>>>(x, W1, Afb, N, K0, F1);
        k_aggregate4<128><<<blocks(N, 8), 256, 0, stream>>>(Afb, starts, csr, dinv, b1, Bfb, N, 1);
        k_gemm_naive<<<blocks((long)N * F2, BLK), BLK, 0, stream>>>(Bfb, W2, Afb, N, F1, F2);
        k_aggregate4<128><<<blocks(N, 8), 256, 0, stream>>>(Afb, starts, csr, dinv, b2, Bfb, N, 1);
        k_gemm_naive<<<blocks((long)N * F3, BLK), BLK, 0, stream>>>(Bfb, W3, Afb, N, F2, F3);
        k_aggregate4<64><<<blocks(N, 16), 256, 0, stream>>>(Afb, starts, csr, dinv, b3, Bfb, N, 0);
        k_pool<<<Gn, F3, 0, stream>>>(Bfb, batch, N, F3, pooled);
        k_final<<<blocks(Gn * C, BLK), BLK, 0, stream>>>(pooled, Wl, bl, (float*)d_out, Gn, F3, C);
    }
}

// Round 11
// 207.532 us; speedup vs baseline: 1.9018x; 1.1152x over previous
//
#include <hip/hip_runtime.h>
#include <hip/hip_fp16.h>

typedef _Float16 f16;
typedef f16 f16x8 __attribute__((ext_vector_type(8)));
typedef float f32x4 __attribute__((ext_vector_type(4)));

// ---------------- utility kernels ----------------

__global__ void k_zero_i32(int* __restrict__ p, int n) {
    int i = blockIdx.x * blockDim.x + threadIdx.x;
    if (i < n) p[i] = 0;
}

__global__ void k_count(const int* __restrict__ col, int E, int* __restrict__ cnt) {
    int e = blockIdx.x * blockDim.x + threadIdx.x;
    if (e < E) atomicAdd(&cnt[col[e]], 1);
}

// ---- 3-pass parallel exclusive scan over cnt[0..N) -> starts[0..N] ----
__global__ void k_bsum(const int* __restrict__ cnt, int N, int* __restrict__ bsum) {
    __shared__ int wt[4];
    int t = threadIdx.x;
    int i0 = blockIdx.x * 1024 + t * 4;
    int s = 0;
    #pragma unroll
    for (int j = 0; j < 4; ++j) { int i = i0 + j; if (i < N) s += cnt[i]; }
    #pragma unroll
    for (int off = 32; off > 0; off >>= 1) s += __shfl_down(s, off, 64);
    if ((t & 63) == 0) wt[t >> 6] = s;
    __syncthreads();
    if (t == 0) bsum[blockIdx.x] = wt[0] + wt[1] + wt[2] + wt[3];
}

__global__ void k_bscan(int* __restrict__ bsum, int nb, int* __restrict__ starts, int N) {
    int lane = threadIdx.x;
    int carry = 0;
    for (int base = 0; base < nb; base += 64) {
        int i = base + lane;
        int v = (i < nb) ? bsum[i] : 0;
        int s = v;
        #pragma unroll
        for (int off = 1; off < 64; off <<= 1) {
            int u = __shfl_up(s, off, 64);
            if (lane >= off) s += u;
        }
        if (i < nb) bsum[i] = carry + s - v;
        carry += __shfl(s, 63, 64);
    }
    if (lane == 0) starts[N] = carry;
}

// pass 3 (+fused dinv)
__global__ void k_scan_apply(const int* __restrict__ cnt, const int* __restrict__ bsum,
                             int* __restrict__ starts, float* __restrict__ dinv, int N) {
    __shared__ int wt[4];
    int t = threadIdx.x;
    int lane = t & 63;
    int w = t >> 6;
    int i0 = blockIdx.x * 1024 + t * 4;
    int v[4];
    int ts = 0;
    #pragma unroll
    for (int j = 0; j < 4; ++j) { int i = i0 + j; v[j] = (i < N) ? cnt[i] : 0; ts += v[j]; }
    int s = ts;
    #pragma unroll
    for (int off = 1; off < 64; off <<= 1) {
        int u = __shfl_up(s, off, 64);
        if (lane >= off) s += u;
    }
    if (lane == 63) wt[w] = s;
    __syncthreads();
    int woff = 0;
    if (w > 0) woff = wt[0];
    if (w > 1) woff += wt[1];
    if (w > 2) woff += wt[2];
    int base = bsum[blockIdx.x] + woff + (s - ts);
    int run = base;
    #pragma unroll
    for (int j = 0; j < 4; ++j) {
        int i = i0 + j;
        if (i < N) {
            starts[i] = run;
            dinv[i] = rsqrtf((float)v[j] + 1.0f);
        }
        run += v[j];
    }
}

// XCD-windowed CSR fill
__global__ void k_fill_xcd(const int* __restrict__ row, const int* __restrict__ col, int E,
                           const int* __restrict__ starts, int* __restrict__ cnt,
                           int* __restrict__ csr, int N) {
    const int w = blockIdx.x & 7;
    const int chunk = blockIdx.x >> 3;
    const int nchunks = gridDim.x >> 3;
    const int W = (N + 7) / 8;
    const int c0 = w * W;
    const int c1 = min(N, c0 + W);
    const int stride = nchunks * blockDim.x;
    for (int e = chunk * blockDim.x + threadIdx.x; e < E; e += stride) {
        int c = col[e];
        if (c >= c0 && c < c1) {
            int pos = starts[c] + atomicSub(&cnt[c], 1) - 1;
            csr[pos] = row[e];
        }
    }
}

// x fp32 -> fp16
__global__ void k_f2h(const float* __restrict__ src, __half* __restrict__ dst, long n) {
    long i = ((long)blockIdx.x * blockDim.x + threadIdx.x) * 4;
    if (i + 3 < n) {
        float4 v = *(const float4*)&src[i];
        __half2 h0 = __floats2half2_rn(v.x, v.y);
        __half2 h1 = __floats2half2_rn(v.z, v.w);
        uint2 q; q.x = *(unsigned int*)&h0; q.y = *(unsigned int*)&h1;
        *(uint2*)&dst[i] = q;
    } else {
        for (long j = i; j < n; ++j) dst[j] = __float2half_rn(src[j]);
    }
}

// all three weights: W[K][M] fp32 -> Wt[m*KP + k] fp16 (transposed, padded)
__global__ void k_wprep3(const float* __restrict__ W1, const float* __restrict__ W2,
                         const float* __restrict__ W3, f16* __restrict__ Wt1,
                         f16* __restrict__ Wt2, f16* __restrict__ Wt3) {
    int idx = blockIdx.x * blockDim.x + threadIdx.x;
    if (idx < 8192) {                      // W1: 64x128 -> [128][72]
        int k = idx >> 7, m = idx & 127;
        Wt1[m * 72 + k] = (f16)W1[idx];
    } else if (idx < 24576) {              // W2: 128x128 -> [128][136]
        int j = idx - 8192;
        int k = j >> 7, m = j & 127;
        Wt2[m * 136 + k] = (f16)W2[j];
    } else if (idx < 32768) {              // W3: 128x64 -> [64][136]
        int j = idx - 24576;
        int k = j >> 6, m = j & 63;
        Wt3[m * 136 + k] = (f16)W3[j];
    }
}

__global__ void k_zero_f32(float* __restrict__ p, int n) {
    int i = blockIdx.x * blockDim.x + threadIdx.x;
    if (i < n) p[i] = 0.0f;
}

// ---------------- MFMA fp16 GEMM ----------------

template<int K, int M, bool BIAS, bool RELU, typename OT>
__global__ __launch_bounds__(256) void k_gemm_mfma(const f16* __restrict__ A,
                                                   const f16* __restrict__ Wt,
                                                   const float* __restrict__ bias,
                                                   OT* __restrict__ P, int N) {
    constexpr int KP = K + 8;
    constexpr int KK = K / 32;
    __shared__ f16 Wl[M * KP];
    const int t = threadIdx.x;
    constexpr int CH = (M * KP * 2) / 16;
    {
        const uint4* src = (const uint4*)Wt;
        uint4* dst = (uint4*)Wl;
        for (int i = t; i < CH; i += 256) dst[i] = src[i];
    }
    __syncthreads();
    const int lane = t & 63;
    const int wave = t >> 6;
    const int r = lane & 15;
    const int q = lane >> 4;
    const int arow = blockIdx.x * 64 + wave * 16 + r;
    f16x8 a[KK];
    #pragma unroll
    for (int kk = 0; kk < KK; ++kk) {
        if (arow < N) a[kk] = *(const f16x8*)&A[(long)arow * K + kk * 32 + q * 8];
        else { f16x8 z = {0, 0, 0, 0, 0, 0, 0, 0}; a[kk] = z; }
    }
    const int drow0 = blockIdx.x * 64 + wave * 16 + q * 4;
    #pragma unroll
    for (int ct = 0; ct < M / 16; ++ct) {
        const int col = ct * 16 + r;
        f32x4 acc = {0.f, 0.f, 0.f, 0.f};
        #pragma unroll
        for (int kk = 0; kk < KK; ++kk) {
            f16x8 b = *(const f16x8*)&Wl[col * KP + kk * 32 + q * 8];
            acc = __builtin_amdgcn_mfma_f32_16x16x32_f16(a[kk], b, acc, 0, 0, 0);
        }
        float bb = BIAS ? bias[col] : 0.f;
        #pragma unroll
        for (int g = 0; g < 4; ++g) {
            int rr = drow0 + g;
            if (rr < N) {
                float v = acc[g] + bb;
                if (RELU) v = fmaxf(v, 0.f);
                if constexpr (__is_same(OT, f16)) P[(long)rr * M + col] = (f16)v;
                else P[(long)rr * M + col] = v;
            }
        }
    }
}

// ---------------- fp16-gather aggregation, 4-wide neighbor unroll ----------------

template<int M, bool BIAS, bool RELU, typename OT>
__global__ void k_agg16(const __half* __restrict__ P16, const int* __restrict__ starts,
                        const int* __restrict__ csr, const float* __restrict__ dinv,
                        const float* __restrict__ b, OT* __restrict__ H, int N) {
    constexpr int TPN = M / 8;
    constexpr int NPB = 256 / TPN;
    int local = threadIdx.x / TPN;
    int fq = threadIdx.x % TPN;
    int f0 = fq * 8;
    int c = blockIdx.x * NPB + local;
    if (c >= N) return;
    int s = starts[c], e = starts[c + 1];
    float acc[8] = {};
    int i = s;
    for (; i + 3 < e; i += 4) {
        int r0 = csr[i], r1 = csr[i + 1], r2 = csr[i + 2], r3 = csr[i + 3];
        float d0 = dinv[r0], d1 = dinv[r1], d2 = dinv[r2], d3 = dinv[r3];
        uint4 u0 = *(const uint4*)&P16[(long)r0 * M + f0];
        uint4 u1 = *(const uint4*)&P16[(long)r1 * M + f0];
        uint4 u2 = *(const uint4*)&P16[(long)r2 * M + f0];
        uint4 u3 = *(const uint4*)&P16[(long)r3 * M + f0];
        const __half2* h0 = (const __half2*)&u0;
        const __half2* h1 = (const __half2*)&u1;
        const __half2* h2 = (const __half2*)&u2;
        const __half2* h3 = (const __half2*)&u3;
        #pragma unroll
        for (int j = 0; j < 4; ++j) {
            float2 v0 = __half22float2(h0[j]);
            float2 v1 = __half22float2(h1[j]);
            float2 v2 = __half22float2(h2[j]);
            float2 v3 = __half22float2(h3[j]);
            acc[2 * j]     += v0.x * d0 + v1.x * d1 + v2.x * d2 + v3.x * d3;
            acc[2 * j + 1] += v0.y * d0 + v1.y * d1 + v2.y * d2 + v3.y * d3;
        }
    }
    for (; i < e; ++i) {
        int r0 = csr[i];
        float d0 = dinv[r0];
        uint4 u0 = *(const uint4*)&P16[(long)r0 * M + f0];
        const __half2* h0 = (const __half2*)&u0;
        #pragma unroll
        for (int j = 0; j < 4; ++j) {
            float2 v0 = __half22float2(h0[j]);
            acc[2 * j]     += v0.x * d0;
            acc[2 * j + 1] += v0.y * d0;
        }
    }
    float dc = dinv[c];
    float dc2 = dc * dc;
    uint4 us = *(const uint4*)&P16[(long)c * M + f0];
    const __half2* hs = (const __half2*)&us;
    float v[8];
    #pragma unroll
    for (int j = 0; j < 4; ++j) {
        float2 fs = __half22float2(hs[j]);
        v[2 * j]     = dc * acc[2 * j]     + dc2 * fs.x;
        v[2 * j + 1] = dc * acc[2 * j + 1] + dc2 * fs.y;
    }
    if (BIAS) {
        float4 bb0 = *(const float4*)&b[f0];
        float4 bb1 = *(const float4*)&b[f0 + 4];
        v[0] += bb0.x; v[1] += bb0.y; v[2] += bb0.z; v[3] += bb0.w;
        v[4] += bb1.x; v[5] += bb1.y; v[6] += bb1.z; v[7] += bb1.w;
    }
    if (RELU) {
        #pragma unroll
        for (int j = 0; j < 8; ++j) v[j] = fmaxf(v[j], 0.f);
    }
    if constexpr (__is_same(OT, __half)) {
        __half2 h0 = __floats2half2_rn(v[0], v[1]);
        __half2 h1 = __floats2half2_rn(v[2], v[3]);
        __half2 h2 = __floats2half2_rn(v[4], v[5]);
        __half2 h3 = __floats2half2_rn(v[6], v[7]);
        uint4 qo;
        qo.x = *(unsigned int*)&h0; qo.y = *(unsigned int*)&h1;
        qo.z = *(unsigned int*)&h2; qo.w = *(unsigned int*)&h3;
        *(uint4*)&H[(long)c * M + f0] = qo;
    } else {
        *(float4*)&H[(long)c * M + f0]     = make_float4(v[0], v[1], v[2], v[3]);
        *(float4*)&H[(long)c * M + f0 + 4] = make_float4(v[4], v[5], v[6], v[7]);
    }
}

// ---------------- fp32 fallback kernels (unexpected shapes) ----------------

__global__ void k_gemm_naive(const float* __restrict__ X, const float* __restrict__ W,
                             float* __restrict__ P, int N, int K, int M) {
    long idx = (long)blockIdx.x * blockDim.x + threadIdx.x;
    long total = (long)N * M;
    if (idx >= total) return;
    int n = (int)(idx / M);
    int m = (int)(idx - (long)n * M);
    const float* xr = X + (long)n * K;
    float acc = 0.0f;
    for (int k = 0; k < K; ++k) acc += xr[k] * W[k * M + m];
    P[idx] = acc;
}

template<int M>
__global__ void k_aggregate4(const float* __restrict__ P, const int* __restrict__ starts,
                             const int* __restrict__ csr, const float* __restrict__ dinv,
                             const float* __restrict__ b, float* __restrict__ H,
                             int N, int do_relu) {
    constexpr int TPN = M / 4;
    constexpr int NPB = 256 / TPN;
    int local = threadIdx.x / TPN;
    int fq = threadIdx.x % TPN;
    int c = blockIdx.x * NPB + local;
    if (c >= N) return;
    int s = starts[c], e = starts[c + 1];
    float4 acc = make_float4(0.f, 0.f, 0.f, 0.f);
    for (int i = s; i < e; ++i) {
        int r = csr[i];
        float dr = dinv[r];
        float4 p = *(const float4*)&P[(long)r * M + fq * 4];
        acc.x += p.x * dr; acc.y += p.y * dr; acc.z += p.z * dr; acc.w += p.w * dr;
    }
    float dc = dinv[c];
    float dc2 = dc * dc;
    float4 ps = *(const float4*)&P[(long)c * M + fq * 4];
    float4 bb = *(const float4*)&b[fq * 4];
    float4 v;
    v.x = dc * acc.x + dc2 * ps.x + bb.x;
    v.y = dc * acc.y + dc2 * ps.y + bb.y;
    v.z = dc * acc.z + dc2 * ps.z + bb.z;
    v.w = dc * acc.w + dc2 * ps.w + bb.w;
    if (do_relu) {
        v.x = fmaxf(v.x, 0.f); v.y = fmaxf(v.y, 0.f);
        v.z = fmaxf(v.z, 0.f); v.w = fmaxf(v.w, 0.f);
    }
    *(float4*)&H[(long)c * M + fq * 4] = v;
}

// ---------------- pooling + classifier ----------------

__device__ __forceinline__ int lower_bound_i(const int* __restrict__ a, int n, int key) {
    int lo = 0, hi = n;
    while (lo < hi) { int mid = (lo + hi) >> 1; if (a[mid] < key) lo = mid + 1; else hi = mid; }
    return lo;
}

// node-parallel partial pooling: batch is sorted, so each thread's contiguous
// 16-node run spans ~1-2 graphs -> register accumulate, atomicAdd at boundaries.
// pooled[g][f] accumulates SUMS (division by count happens in k_final2).
__global__ void k_pool_part(const float* __restrict__ H, const int* __restrict__ batch,
                            int N, float* __restrict__ pooled) {
    const int f = threadIdx.x & 63;
    const int ln = threadIdx.x >> 6;          // 4 node-lanes
    int n0 = blockIdx.x * 64 + ln * 16;
    int n1 = min(n0 + 16, N);
    float acc = 0.f;
    int cur = -1;
    for (int n = n0; n < n1; ++n) {
        int g = batch[n];
        if (g != cur) {
            if (cur >= 0) atomicAdd(&pooled[cur * 64 + f], acc);
            acc = 0.f;
            cur = g;
        }
        acc += H[(long)n * 64 + f];
    }
    if (cur >= 0) atomicAdd(&pooled[cur * 64 + f], acc);
}

// per-graph classifier: divide pooled sums by count, apply Wl/bl
__global__ void k_final2(const float* __restrict__ pooled, const int* __restrict__ batch,
                         int N, const float* __restrict__ Wl, const float* __restrict__ bl,
                         float* __restrict__ out, int C) {
    __shared__ float pl[64];
    int g = blockIdx.x;
    int f = threadIdx.x;     // 64 threads
    int lo = lower_bound_i(batch, N, g);
    int hi = lower_bound_i(batch, N, g + 1);
    float inv = 1.0f / fmaxf((float)(hi - lo), 1.0f);
    pl[f] = pooled[g * 64 + f] * inv;
    __syncthreads();
    if (f < C) {
        float o = bl[f];
        #pragma unroll 8
        for (int k = 0; k < 64; ++k) o += pl[k] * Wl[k * C + f];
        out[g * C + f] = o;
    }
}

__global__ void k_pool(const float* __restrict__ H, const int* __restrict__ batch,
                       int N, int M, float* __restrict__ pooled) {
    int g = blockIdx.x;
    int f = threadIdx.x;
    int lo = lower_bound_i(batch, N, g);
    int hi = lower_bound_i(batch, N, g + 1);
    float acc = 0.0f;
    for (int n = lo; n < hi; ++n) acc += H[(long)n * M + f];
    float inv = 1.0f / fmaxf((float)(hi - lo), 1.0f);
    pooled[(long)g * M + f] = acc * inv;
}

__global__ void k_final(const float* __restrict__ pooled, const float* __restrict__ Wl,
                        const float* __restrict__ bl, float* __restrict__ out,
                        int Gn, int F, int C) {
    int idx = blockIdx.x * blockDim.x + threadIdx.x;
    if (idx >= Gn * C) return;
    int g = idx / C;
    int j = idx - g * C;
    float acc = bl[j];
    for (int f = 0; f < F; ++f) acc += pooled[g * F + f] * Wl[f * C + j];
    out[idx] = acc;
}

// ---------------- launch ----------------

extern "C" void kernel_launch(void* const* d_in, const int* in_sizes, int n_in,
                              void* d_out, int out_size, void* d_ws, size_t ws_size,
                              hipStream_t stream) {
    const float* x  = (const float*)d_in[0];
    const int*   ei = (const int*)d_in[1];
    const int*   batch = (const int*)d_in[2];
    const float* W1 = (const float*)d_in[3];
    const float* b1 = (const float*)d_in[4];
    const float* W2 = (const float*)d_in[5];
    const float* b2 = (const float*)d_in[6];
    const float* W3 = (const float*)d_in[7];
    const float* b3 = (const float*)d_in[8];
    const float* Wl = (const float*)d_in[9];
    const float* bl = (const float*)d_in[10];

    const int N  = in_sizes[2];          // 50000
    const int E  = in_sizes[1] / 2;      // 800000
    const int C  = in_sizes[10];         // 10
    const int Gn = out_size / C;         // 512
    const int F1 = in_sizes[4];          // 128
    const int F2 = in_sizes[6];          // 128
    const int F3 = in_sizes[8];          // 64
    const int K0 = in_sizes[0] / N;      // 64

    const int* row = ei;
    const int* col = ei + E;

    // workspace layout (64B-aligned chunks)
    char* base = (char*)d_ws;
    size_t off = 0;
    auto alloc = [&](size_t bytes) {
        off = (off + 63) & ~(size_t)63;
        void* p = base + off;
        off += bytes;
        return p;
    };
    int* cnt     = (int*)alloc((size_t)N * 4);
    int* starts  = (int*)alloc((size_t)(N + 1) * 4);
    int* bsum    = (int*)alloc(256 * 4);
    int* csr     = (int*)alloc((size_t)E * 4);
    float* dinv  = (float*)alloc((size_t)N * 4);
    __half* X16  = (__half*)alloc((size_t)N * 64 * 2);
    __half* AX16 = (__half*)alloc((size_t)N * 64 * 2);
    __half* H1   = (__half*)alloc((size_t)N * 128 * 2);
    __half* P16a = (__half*)alloc((size_t)N * 128 * 2);
    __half* B16  = (__half*)alloc((size_t)N * 128 * 2);
    __half* P16b = (__half*)alloc((size_t)N * 64 * 2);
    float* H3    = (float*)alloc((size_t)N * 64 * 4);
    f16* Wt1     = (f16*)alloc((size_t)128 * 72 * 2);
    f16* Wt2     = (f16*)alloc((size_t)128 * 136 * 2);
    f16* Wt3     = (f16*)alloc((size_t)64 * 136 * 2);
    float* pooled = (float*)alloc((size_t)Gn * 64 * 4);
    float* Afb   = (float*)alloc((size_t)N * 128 * 4);
    float* Bfb   = (float*)alloc((size_t)N * 128 * 4);

    const int BLK = 256;
    auto blocks = [](long n, int b) { return (int)((n + b - 1) / b); };
    const int nb = blocks(N, 1024);

    // --- build CSR (+ dinv fused into scan_apply) ---
    k_zero_i32<<<blocks(N, BLK), BLK, 0, stream>>>(cnt, N);
    k_count<<<blocks(E, BLK), BLK, 0, stream>>>(col, E, cnt);
    k_bsum<<<nb, 256, 0, stream>>>(cnt, N, bsum);
    k_bscan<<<1, 64, 0, stream>>>(bsum, nb, starts, N);
    k_scan_apply<<<nb, 256, 0, stream>>>(cnt, bsum, starts, dinv, N);
    k_fill_xcd<<<128 * 8, 256, 0, stream>>>(row, col, E, starts, cnt, csr, N);

    const bool fast = (K0 == 64 && F1 == 128 && F2 == 128 && F3 == 64);

    if (fast) {
        k_f2h<<<blocks(((long)N * 64 + 3) / 4, BLK), BLK, 0, stream>>>(x, X16, (long)N * 64);
        k_wprep3<<<128, 256, 0, stream>>>(W1, W2, W3, Wt1, Wt2, Wt3);
        k_zero_f32<<<blocks(Gn * 64, BLK), BLK, 0, stream>>>(pooled, Gn * 64);

        // layer 1 (reordered): H1 = relu( (A_hat X) W1 + b1 )
        k_agg16<64, false, false, __half><<<blocks(N, 32), 256, 0, stream>>>(X16, starts, csr, dinv, nullptr, AX16, N);
        k_gemm_mfma<64, 128, true, true, f16><<<blocks(N, 64), 256, 0, stream>>>((const f16*)AX16, Wt1, b1, (f16*)H1, N);
        // layer 2: B16 = relu( A_hat (H1 W2) + b2 )
        k_gemm_mfma<128, 128, false, false, f16><<<blocks(N, 64), 256, 0, stream>>>((const f16*)H1, Wt2, nullptr, (f16*)P16a, N);
        k_agg16<128, true, true, __half><<<blocks(N, 16), 256, 0, stream>>>(P16a, starts, csr, dinv, b2, B16, N);
        // layer 3: H3 = A_hat (B16 W3) + b3
        k_gemm_mfma<128, 64, false, false, f16><<<blocks(N, 64), 256, 0, stream>>>((const f16*)B16, Wt3, nullptr, (f16*)P16b, N);
        k_agg16<64, true, false, float><<<blocks(N, 32), 256, 0, stream>>>(P16b, starts, csr, dinv, b3, H3, N);
        // node-parallel pool + per-graph classifier
        k_pool_part<<<blocks(N, 64), 256, 0, stream>>>(H3, batch, N, pooled);
        k_final2<<<Gn, 64, 0, stream>>>(pooled, batch, N, Wl, bl, (float*)d_out, C);
    } else {
        k_gemm_naive<<<blocks((long)N * F1, BLK), BLK, 0, stream>>>(x, W1, Afb, N, K0, F1);
        k_aggregate4<128><<<blocks(N, 8), 256, 0, stream>>>(Afb, starts, csr, dinv, b1, Bfb, N, 1);
        k_gemm_naive<<<blocks((long)N * F2, BLK), BLK, 0, stream>>>(Bfb, W2, Afb, N, F1, F2);
        k_aggregate4<128><<<blocks(N, 8), 256, 0, stream>>>(Afb, starts, csr, dinv, b2, Bfb, N, 1);
        k_gemm_naive<<<blocks((long)N * F3, BLK), BLK, 0, stream>>>(Bfb, W3, Afb, N, F2, F3);
        k_aggregate4<64><<<blocks(N, 16), 256, 0, stream>>>(Afb, starts, csr, dinv, b3, Bfb, N, 0);
        k_pool<<<Gn, F3, 0, stream>>>(Bfb, batch, N, F3, pooled);
        k_final<<<blocks(Gn * C, BLK), BLK, 0, stream>>>(pooled, Wl, bl, (float*)d_out, Gn, F3, C);
    }
}